// Round 5
// baseline (1362.139 us; speedup 1.0000x reference)
//
#include <hip/hip_runtime.h>
#include <math.h>

#define Bd 4
#define Cd 512
#define Hd 48
#define Wd 48
#define HWd (Hd * Wd)          // 2304
#define Nd (Bd * HWd)          // 9216
#define BN_EPS 1e-5f

#define QBLK 64
#define KBLK 128
#define NKS 2
#define KSLEN (Nd / NKS)       // 4608
#define AITERS (KSLEN / KBLK)  // 36

typedef _Float16 half8 __attribute__((ext_vector_type(8)));
typedef _Float16 h4 __attribute__((ext_vector_type(4)));
typedef float f32x16 __attribute__((ext_vector_type(16)));

#define KSWZ(row) (((row) & 31) << 4)
#define PSWZ(row) ((((row) & 7) << 4) | ((((row) >> 3) & 1) << 3))

__device__ inline void gload_lds16(const void* g, void* l) {
    __builtin_amdgcn_global_load_lds((const __attribute__((address_space(1))) void*)g,
                                     (__attribute__((address_space(3))) void*)l, 16, 0, 0);
}

// barrier that does NOT drain vmcnt (keeps staged global_load_lds in flight)
__device__ inline void bar_lgkm() {
    asm volatile("s_waitcnt lgkmcnt(0)" ::: "memory");
    __builtin_amdgcn_sched_barrier(0);
    __builtin_amdgcn_s_barrier();
    __builtin_amdgcn_sched_barrier(0);
}
// barrier that drains everything (staging landed)
__device__ inline void bar_all() {
    asm volatile("s_waitcnt vmcnt(0) lgkmcnt(0)" ::: "memory");
    __builtin_amdgcn_sched_barrier(0);
    __builtin_amdgcn_s_barrier();
    __builtin_amdgcn_sched_barrier(0);
}

// ---------------- tiled fp32 linear (1x1 conv), templated layouts ----------------
// INM: 0 = BCHW f32 input, 2 = ch-major f32 [Cd][Nd]
// OUTM: 0 = fp16 token-major [Nd][Cd], 1 = fp16 ch-major [Cd][Nd], 2 = f32 BCHW
template<int INM, int OUTM>
__global__ __launch_bounds__(256) void linear_k(const float* __restrict__ in,
                                                const float* __restrict__ w,
                                                const float* __restrict__ bias,
                                                void* __restrict__ outp) {
    __shared__ float Asub[16][68];
    __shared__ float Bsub[64][17];

    const int tid = threadIdx.x;
    const int tx = tid & 15;
    const int ty = tid >> 4;
    const int n0 = blockIdx.x * 64;
    const int o0 = blockIdx.y * 64;
    const int b  = n0 / HWd;
    const int hw0 = n0 % HWd;

    float acc[4][4] = {};

    for (int k0 = 0; k0 < Cd; k0 += 16) {
        {
            int r = tid >> 6;
            int col = tid & 63;
            #pragma unroll
            for (int i = 0; i < 4; ++i) {
                int c_l = r * 4 + i;
                if (INM == 0)
                    Asub[c_l][col] = in[(size_t)(b * Cd + k0 + c_l) * HWd + hw0 + col];
                else
                    Asub[c_l][col] = in[(size_t)(k0 + c_l) * Nd + n0 + col];
            }
        }
        {
            int c_l = tid & 15;
            int o_l = tid >> 4;
            #pragma unroll
            for (int i = 0; i < 4; ++i) {
                int o = o_l + 16 * i;
                Bsub[o][c_l] = w[(size_t)(o0 + o) * Cd + k0 + c_l];
            }
        }
        __syncthreads();
        #pragma unroll
        for (int k = 0; k < 16; ++k) {
            float4 av = *(const float4*)&Asub[k][tx * 4];
            float a[4] = {av.x, av.y, av.z, av.w};
            float bb[4];
            #pragma unroll
            for (int j = 0; j < 4; ++j) bb[j] = Bsub[ty * 4 + j][k];
            #pragma unroll
            for (int i = 0; i < 4; ++i)
                #pragma unroll
                for (int j = 0; j < 4; ++j)
                    acc[i][j] = fmaf(a[i], bb[j], acc[i][j]);
        }
        __syncthreads();
    }

    #pragma unroll
    for (int j = 0; j < 4; ++j) {
        float bj = bias[o0 + ty * 4 + j];
        #pragma unroll
        for (int i = 0; i < 4; ++i) acc[i][j] += bj;
    }

    if (OUTM == 0) {
        _Float16* o16 = (_Float16*)outp;
        #pragma unroll
        for (int i = 0; i < 4; ++i)
            #pragma unroll
            for (int j = 0; j < 4; ++j)
                o16[(size_t)(n0 + tx * 4 + i) * Cd + o0 + ty * 4 + j] = (_Float16)acc[i][j];
    } else if (OUTM == 1) {
        _Float16* o16 = (_Float16*)outp;
        #pragma unroll
        for (int j = 0; j < 4; ++j)
            #pragma unroll
            for (int i = 0; i < 4; ++i)
                o16[(size_t)(o0 + ty * 4 + j) * Nd + n0 + tx * 4 + i] = (_Float16)acc[i][j];
    } else {
        float* of = (float*)outp;
        #pragma unroll
        for (int j = 0; j < 4; ++j) {
            int o = o0 + ty * 4 + j;
            size_t base = (size_t)(b * Cd + o) * HWd + hw0 + tx * 4;
            #pragma unroll
            for (int i = 0; i < 4; ++i) of[base + i] = acc[i][j];
        }
    }
}

// ---------------- MFMA flash attention (fp16 inputs, fp32 accum) ----------------
// Swapped-operand: S^T = mfma(K, Q), O^T = mfma(xtT, P^T).
// Pipelined K staging: stage tile it+1 after barrier#1 of tile it (K unused in PV),
// raw lgkm-only barriers mid-iter, single vmcnt-drain at end of iter.
__global__ __launch_bounds__(512, 2) void attn_mfma_k(
    const _Float16* __restrict__ lhsH,   // [Nd][512]
    const _Float16* __restrict__ rhsH,   // [Nd][512]
    const _Float16* __restrict__ xtT,    // [512][Nd]
    float* __restrict__ part,            // [NKS][512][Nd]
    float* __restrict__ marr,            // [NKS][Nd]
    float* __restrict__ larr) {          // [NKS][Nd]
    __shared__ _Float16 Kl[KBLK * 512];  // 128 KB, rows 1KB, KSWZ swizzle
    __shared__ _Float16 Pl[QBLK * KBLK]; // 16 KB, rows 256B, PSWZ swizzle
    __shared__ float m_s[QBLK], l_s[QBLK], corr_s[QBLK];
    __shared__ float tm_s[4][QBLK], ls_s[4][QBLK];

    const int tid = threadIdx.x;
    const int wave = tid >> 6;
    const int lane = tid & 63;
    const int l31 = lane & 31;
    const int hi32 = lane >> 5;

    const int nqb = Nd / QBLK;           // 144
    const int qb = blockIdx.x % nqb;
    const int ks = blockIdx.x / nqb;
    const int q0 = qb * QBLK;
    const int k0g = ks * KSLEN;

    const int kt = wave & 3;             // key sub-tile (QK phase)
    const int qg = wave >> 2;            // query tile (QK phase)

    // Q fragments in registers (this wave's 32-query tile, full d=512)
    half8 qf[32];
    {
        const _Float16* qrow = lhsH + (size_t)(q0 + qg * 32 + l31) * 512 + hi32 * 8;
        #pragma unroll
        for (int f = 0; f < 32; ++f)
            qf[f] = *(const half8*)(qrow + f * 16);
    }

    f32x16 o_acc[2][2];
    #pragma unroll
    for (int a = 0; a < 2; ++a)
        #pragma unroll
        for (int b = 0; b < 2; ++b)
            #pragma unroll
            for (int r = 0; r < 16; ++r) o_acc[a][b][r] = 0.f;

    if (tid < QBLK) { m_s[tid] = -INFINITY; l_s[tid] = 0.f; }

    // ---- prologue: stage tile 0 (16 rows per wave, pre-swizzled source)
    {
        const int kb = k0g;
        #pragma unroll
        for (int i = 0; i < 16; ++i) {
            int row = wave * 16 + i;
            int sb = (lane * 16) ^ KSWZ(row);
            gload_lds16((const char*)(rhsH + (size_t)(kb + row) * 512) + sb,
                        (char*)Kl + row * 1024);
        }
    }
    bar_all();

    for (int it = 0; it < AITERS; ++it) {
        const int kb = k0g + it * KBLK;

        float m_old = m_s[qg * 32 + l31];

        // ---- QK^T (swapped): S^T frag, 32 MFMAs over d=512
        f32x16 s;
        #pragma unroll
        for (int r = 0; r < 16; ++r) s[r] = 0.f;
        {
            const int row = kt * 32 + l31;
            const char* krow = (const char*)Kl + row * 1024;
            const int swz = KSWZ(row);
            #pragma unroll
            for (int f = 0; f < 32; ++f) {
                half8 a = *(const half8*)(krow + ((32 * f + 16 * hi32) ^ swz));
                s = __builtin_amdgcn_mfma_f32_32x32x16_f16(a, qf[f], s, 0, 0, 0);
            }
        }

        // ---- tile max (this wave's 32 keys for query l31)
        float tmax = s[0];
        #pragma unroll
        for (int r = 1; r < 16; ++r) tmax = fmaxf(tmax, s[r]);
        tmax = fmaxf(tmax, __shfl_xor(tmax, 32));
        if (lane < 32) tm_s[kt][qg * 32 + lane] = tmax;

        bar_lgkm();   // BAR#1: all QK reads of Kl drained; tm_s visible

        // ---- stage NEXT tile (K unused below; loads fly until end-of-iter)
        if (it + 1 < AITERS) {
            const int kbn = kb + KBLK;
            #pragma unroll
            for (int i = 0; i < 16; ++i) {
                int row = wave * 16 + i;
                int sb = (lane * 16) ^ KSWZ(row);
                gload_lds16((const char*)(rhsH + (size_t)(kbn + row) * 512) + sb,
                            (char*)Kl + row * 1024);
            }
        }

        // ---- softmax: new max, corr, P = exp(s - mn) -> LDS (b64 stores)
        float mn = m_old;
        #pragma unroll
        for (int t = 0; t < 4; ++t) mn = fmaxf(mn, tm_s[t][qg * 32 + l31]);
        float corr = __expf(m_old - mn);

        float psum = 0.f;
        {
            const int qrow = qg * 32 + l31;
            char* prow = (char*)Pl + qrow * 256;
            const int swz = PSWZ(qrow);
            #pragma unroll
            for (int g = 0; g < 4; ++g) {
                float p0 = __expf(s[4 * g + 0] - mn);
                float p1 = __expf(s[4 * g + 1] - mn);
                float p2 = __expf(s[4 * g + 2] - mn);
                float p3 = __expf(s[4 * g + 3] - mn);
                psum += (p0 + p1) + (p2 + p3);
                h4 pk = {(_Float16)p0, (_Float16)p1, (_Float16)p2, (_Float16)p3};
                *(h4*)(prow + ((64 * kt + 16 * g + 8 * hi32) ^ swz)) = pk;
            }
        }
        psum += __shfl_xor(psum, 32);
        if (lane < 32) {
            ls_s[kt][qg * 32 + lane] = psum;
            if (kt == 0) corr_s[qg * 32 + lane] = corr;
        }

        bar_lgkm();   // BAR#2: P, ls_s, corr_s visible

        // ---- state update (kt==0 waves own it; consumed next iter after bar_all)
        if (kt == 0 && lane < 32) {
            int ql = qg * 32 + lane;
            m_s[ql] = mn;
            l_s[ql] = l_s[ql] * corr +
                      ls_s[0][ql] + ls_s[1][ql] + ls_s[2][ql] + ls_s[3][ql];
        }

        // ---- rescale O^T, then PV (wave owns 64-channel slice)
        float c0v = corr_s[l31];
        float c1v = corr_s[32 + l31];
        #pragma unroll
        for (int cht = 0; cht < 2; ++cht)
            #pragma unroll
            for (int r = 0; r < 16; ++r) {
                o_acc[cht][0][r] *= c0v;
                o_acc[cht][1][r] *= c1v;
            }

        {
            const int swz0 = PSWZ(l31);
            const int swz1 = PSWZ(32 + l31);
            const char* pr0 = (const char*)Pl + l31 * 256;
            const char* pr1 = (const char*)Pl + (32 + l31) * 256;
            #pragma unroll
            for (int kf = 0; kf < 8; ++kf) {
                int nb = 32 * kf + 16 * hi32;
                h4 a0 = *(const h4*)(pr0 + ((nb) ^ swz0));
                h4 b0 = *(const h4*)(pr0 + ((nb + 8) ^ swz0));
                h4 a1 = *(const h4*)(pr1 + ((nb) ^ swz1));
                h4 b1 = *(const h4*)(pr1 + ((nb + 8) ^ swz1));
                half8 pb0 = {a0[0], a0[1], a0[2], a0[3], b0[0], b0[1], b0[2], b0[3]};
                half8 pb1 = {a1[0], a1[1], a1[2], a1[3], b1[0], b1[1], b1[2], b1[3]};
                #pragma unroll
                for (int cht = 0; cht < 2; ++cht) {
                    const _Float16* xp = xtT + (size_t)(wave * 64 + cht * 32 + l31) * Nd
                                       + (kb + kf * 16 + hi32 * 8);
                    half8 xa = *(const half8*)xp;
                    o_acc[cht][0] = __builtin_amdgcn_mfma_f32_32x32x16_f16(xa, pb0, o_acc[cht][0], 0, 0, 0);
                    o_acc[cht][1] = __builtin_amdgcn_mfma_f32_32x32x16_f16(xa, pb1, o_acc[cht][1], 0, 0, 0);
                }
            }
        }

        bar_all();    // END: staged tile landed (vmcnt 0), P consumed, state visible
    }

    // ---- epilogue: write unnormalized partials + (m, l)
    #pragma unroll
    for (int cht = 0; cht < 2; ++cht)
        #pragma unroll
        for (int qt = 0; qt < 2; ++qt)
            #pragma unroll
            for (int r = 0; r < 16; ++r) {
                int ch = wave * 64 + cht * 32 + (r & 3) + 8 * (r >> 2) + 4 * hi32;
                int q = q0 + qt * 32 + l31;
                part[((size_t)ks * Cd + ch) * Nd + q] = o_acc[cht][qt][r];
            }
    if (kt == 0 && lane < 32) {
        int ql = qg * 32 + lane;
        marr[(size_t)ks * Nd + q0 + ql] = m_s[ql];
        larr[(size_t)ks * Nd + q0 + ql] = l_s[ql];
    }
}

// ---------------- LSE merge of the NKS key-split partials (in-place into part0) --
__global__ __launch_bounds__(256) void merge_k(float* __restrict__ part,
                                               const float* __restrict__ marr,
                                               const float* __restrict__ larr) {
    int idx = blockIdx.x * 256 + threadIdx.x;
    if (idx >= Cd * Nd) return;
    int q = idx % Nd;
    float m0 = marr[q], m1 = marr[Nd + q];
    float mm = fmaxf(m0, m1);
    float w0 = __expf(m0 - mm), w1 = __expf(m1 - mm);
    float L = larr[q] * w0 + larr[Nd + q] * w1;
    part[idx] = (part[idx] * w0 + part[(size_t)Cd * Nd + idx] * w1) / L;
}

// ---------------- BN stats (per channel, double accumulation) ----------------
__global__ __launch_bounds__(256) void bnstats_k(const float* __restrict__ y,
                                                 const float* __restrict__ gamma,
                                                 const float* __restrict__ beta,
                                                 float* __restrict__ stats) {
    const int c = blockIdx.x;
    const int tid = threadIdx.x;
    double s = 0.0, sq = 0.0;
    for (int b = 0; b < Bd; ++b) {
        const float* p = y + (size_t)(b * Cd + c) * HWd;
        for (int i = tid; i < HWd; i += 256) {
            double v = (double)p[i];
            s += v;
            sq += v * v;
        }
    }
    #pragma unroll
    for (int off = 32; off; off >>= 1) {
        s  += __shfl_xor(s, off, 64);
        sq += __shfl_xor(sq, off, 64);
    }
    __shared__ double ss[4], sqs[4];
    int wid = tid >> 6;
    if ((tid & 63) == 0) { ss[wid] = s; sqs[wid] = sq; }
    __syncthreads();
    if (tid == 0) {
        double S = ss[0] + ss[1] + ss[2] + ss[3];
        double Q = sqs[0] + sqs[1] + sqs[2] + sqs[3];
        double mean = S / (double)Nd;
        double var = Q / (double)Nd - mean * mean;
        float inv = (float)(1.0 / sqrt(var + (double)BN_EPS));
        float sc = gamma[c] * inv;
        stats[c] = sc;
        stats[Cd + c] = beta[c] - (float)mean * sc;
    }
}

__global__ __launch_bounds__(256) void bnapply_k(const float* __restrict__ y,
                                                 const float* __restrict__ stats,
                                                 float* __restrict__ out) {
    int idx = blockIdx.x * 256 + threadIdx.x;
    if (idx >= Bd * Cd * HWd) return;
    int c = (idx / HWd) % Cd;
    float v = fmaf(y[idx], stats[c], stats[Cd + c]);
    out[idx] = fmaxf(v, 0.f);
}

extern "C" void kernel_launch(void* const* d_in, const int* in_sizes, int n_in,
                              void* d_out, int out_size, void* d_ws, size_t ws_size,
                              hipStream_t stream) {
    const float* x     = (const float*)d_in[0];
    const float* depth = (const float*)d_in[1];
    const float* w_rgb = (const float*)d_in[2];
    const float* b_rgb = (const float*)d_in[3];
    const float* w_lhs = (const float*)d_in[4];
    const float* b_lhs = (const float*)d_in[5];
    const float* w_rhs = (const float*)d_in[6];
    const float* b_rhs = (const float*)d_in[7];
    const float* w_dec = (const float*)d_in[8];
    const float* b_dec = (const float*)d_in[9];
    const float* gamma = (const float*)d_in[10];
    const float* beta  = (const float*)d_in[11];
    float* out = (float*)d_out;

    char* wsb = (char*)d_ws;
    const size_t H_BYTES = (size_t)Nd * Cd * 2;      // 9,437,184
    _Float16* lhsH = (_Float16*)wsb;
    _Float16* rhsH = (_Float16*)(wsb + H_BYTES);
    _Float16* xtT  = (_Float16*)(wsb + 2 * H_BYTES);
    float* part = (float*)(wsb + 3 * H_BYTES);       // 2 x Cd x Nd f32
    float* marr = part + (size_t)NKS * Cd * Nd;      // 2 x Nd
    float* larr = marr + (size_t)NKS * Nd;
    float* stats = larr + (size_t)NKS * Nd;
    float* ybuf = part + (size_t)Cd * Nd;            // reuse part1 after merge

    dim3 gGemm(Nd / 64, Cd / 64);
    linear_k<0, 0><<<gGemm, 256, 0, stream>>>(depth, w_lhs, b_lhs, lhsH);
    linear_k<0, 0><<<gGemm, 256, 0, stream>>>(depth, w_rhs, b_rhs, rhsH);
    linear_k<0, 1><<<gGemm, 256, 0, stream>>>(x, w_rgb, b_rgb, xtT);

    attn_mfma_k<<<(Nd / QBLK) * NKS, 512, 0, stream>>>(lhsH, rhsH, xtT, part, marr, larr);

    merge_k<<<((size_t)Cd * Nd + 255) / 256, 256, 0, stream>>>(part, marr, larr);

    linear_k<2, 2><<<gGemm, 256, 0, stream>>>(part, w_dec, b_dec, ybuf);

    bnstats_k<<<Cd, 256, 0, stream>>>(ybuf, gamma, beta, stats);
    bnapply_k<<<(Bd * Cd * HWd + 255) / 256, 256, 0, stream>>>(ybuf, stats, out);
}

// Round 6
// 924.213 us; speedup vs baseline: 1.4738x; 1.4738x over previous
//
#include <hip/hip_runtime.h>
#include <math.h>

#define Bd 4
#define Cd 512
#define Hd 48
#define Wd 48
#define HWd (Hd * Wd)          // 2304
#define Nd (Bd * HWd)          // 9216
#define BN_EPS 1e-5f

#define QBLK 32
#define KBLK 128
#define AITERS (Nd / KBLK)     // 72

typedef _Float16 half8 __attribute__((ext_vector_type(8)));
typedef _Float16 h4 __attribute__((ext_vector_type(4)));
typedef _Float16 h2 __attribute__((ext_vector_type(2)));
typedef float f32x16 __attribute__((ext_vector_type(16)));

__device__ inline void gload_lds16(const void* g, void* l) {
    __builtin_amdgcn_global_load_lds((const __attribute__((address_space(1))) void*)g,
                                     (__attribute__((address_space(3))) void*)l, 16, 0, 0);
}

// K-packed fragment index: [kbt][kt][f][lane][8]  (key=token n, ch=o)
__device__ __host__ inline size_t kp_idx(int n, int o) {
    return ((((size_t)(n >> 7) * 4 + ((n >> 5) & 3)) * 32 + (o >> 4)) * 64
            + ((n & 31) + 32 * ((o >> 3) & 1))) * 8 + (o & 7);
}
// V-packed fragment index: [kbt][chg][kf][lane][8]  (key=token n, ch=o)
__device__ __host__ inline size_t vp_idx(int n, int o) {
    return ((((size_t)(n >> 7) * 16 + (o >> 5)) * 8 + ((n >> 4) & 7)) * 64
            + ((o & 31) + 32 * ((n >> 3) & 1))) * 8 + (n & 7);
}

// ---------------- tiled fp32 linear (1x1 conv), templated layouts ----------------
// INM: 0 = BCHW f32, 2 = ch-major f32 [Cd][Nd]
// OUTM: 0 = fp16 token-major [Nd][Cd], 2 = f32 BCHW, 3 = fp16 K-packed, 4 = fp16 V-packed
template<int INM, int OUTM>
__global__ __launch_bounds__(256) void linear_k(const float* __restrict__ in,
                                                const float* __restrict__ w,
                                                const float* __restrict__ bias,
                                                void* __restrict__ outp) {
    __shared__ float Asub[16][68];
    __shared__ float Bsub[64][17];

    const int tid = threadIdx.x;
    const int tx = tid & 15;
    const int ty = tid >> 4;
    const int n0 = blockIdx.x * 64;
    const int o0 = blockIdx.y * 64;
    const int b  = n0 / HWd;
    const int hw0 = n0 % HWd;

    float acc[4][4] = {};

    for (int k0 = 0; k0 < Cd; k0 += 16) {
        {
            int r = tid >> 6;
            int col = tid & 63;
            #pragma unroll
            for (int i = 0; i < 4; ++i) {
                int c_l = r * 4 + i;
                if (INM == 0)
                    Asub[c_l][col] = in[(size_t)(b * Cd + k0 + c_l) * HWd + hw0 + col];
                else
                    Asub[c_l][col] = in[(size_t)(k0 + c_l) * Nd + n0 + col];
            }
        }
        {
            int c_l = tid & 15;
            int o_l = tid >> 4;
            #pragma unroll
            for (int i = 0; i < 4; ++i) {
                int o = o_l + 16 * i;
                Bsub[o][c_l] = w[(size_t)(o0 + o) * Cd + k0 + c_l];
            }
        }
        __syncthreads();
        #pragma unroll
        for (int k = 0; k < 16; ++k) {
            float4 av = *(const float4*)&Asub[k][tx * 4];
            float a[4] = {av.x, av.y, av.z, av.w};
            float bb[4];
            #pragma unroll
            for (int j = 0; j < 4; ++j) bb[j] = Bsub[ty * 4 + j][k];
            #pragma unroll
            for (int i = 0; i < 4; ++i)
                #pragma unroll
                for (int j = 0; j < 4; ++j)
                    acc[i][j] = fmaf(a[i], bb[j], acc[i][j]);
        }
        __syncthreads();
    }

    #pragma unroll
    for (int j = 0; j < 4; ++j) {
        float bj = bias[o0 + ty * 4 + j];
        #pragma unroll
        for (int i = 0; i < 4; ++i) acc[i][j] += bj;
    }

    if (OUTM == 0) {
        _Float16* o16 = (_Float16*)outp;
        #pragma unroll
        for (int i = 0; i < 4; ++i)
            #pragma unroll
            for (int j = 0; j < 4; ++j)
                o16[(size_t)(n0 + tx * 4 + i) * Cd + o0 + ty * 4 + j] = (_Float16)acc[i][j];
    } else if (OUTM == 3) {
        _Float16* o16 = (_Float16*)outp;
        #pragma unroll
        for (int i = 0; i < 4; ++i) {
            int n = n0 + tx * 4 + i;
            h4 v = {(_Float16)acc[i][0], (_Float16)acc[i][1],
                    (_Float16)acc[i][2], (_Float16)acc[i][3]};
            *(h4*)(o16 + kp_idx(n, o0 + ty * 4)) = v;
        }
    } else if (OUTM == 4) {
        _Float16* o16 = (_Float16*)outp;
        #pragma unroll
        for (int j = 0; j < 4; ++j) {
            int o = o0 + ty * 4 + j;
            h4 v = {(_Float16)acc[0][j], (_Float16)acc[1][j],
                    (_Float16)acc[2][j], (_Float16)acc[3][j]};
            *(h4*)(o16 + vp_idx(n0 + tx * 4, o)) = v;
        }
    } else {
        float* of = (float*)outp;
        #pragma unroll
        for (int j = 0; j < 4; ++j) {
            int o = o0 + ty * 4 + j;
            size_t base = (size_t)(b * Cd + o) * HWd + hw0 + tx * 4;
            #pragma unroll
            for (int i = 0; i < 4; ++i) of[base + i] = acc[i][j];
        }
    }
}

// ---------------- MFMA flash attention v3: packed-operand streaming ----------------
// 4 waves, QBLK=32 queries/block, KBLK=128 keys/iter, NKS=1 (no split, no merge).
// Swapped QK: S^T = mfma(K_frag, Q_frag); PV: O^T = mfma(V_frag, P^T_frag).
// K/V fragments streamed coalesced from packed global buffers (L2/L3 resident).
// Q in LDS operand-major [chunk][lane] (conflict-free). P dbuf in LDS.
__global__ __launch_bounds__(256, 3) void attn_v3_k(
    const _Float16* __restrict__ lhsH,   // [Nd][512] token-major
    const _Float16* __restrict__ Kp,     // packed
    const _Float16* __restrict__ Vp,     // packed
    float* __restrict__ enh) {           // [512][Nd] ch-major
    __shared__ _Float16 Qs[64 * 256];    // [64 chunks][32 q][8] = 32KB
    __shared__ _Float16 Pl[2][16 * 256]; // [16 kchunk][32 q][8] = 8KB each
    __shared__ float tm_s[4][32], ls_s[4][32];

    const int tid = threadIdx.x;
    const int wave = tid >> 6;           // = kt (key sub-tile)
    const int lane = tid & 63;
    const int l31 = lane & 31;
    const int hi32 = lane >> 5;
    const int q0 = blockIdx.x * QBLK;

    // ---- stage Q once: 32 x 1KB, operand-major (per-lane global source)
    #pragma unroll
    for (int j = 0; j < 8; ++j) {
        int instr = wave * 8 + j;
        int chunk = 2 * instr + hi32;
        gload_lds16(lhsH + (size_t)(q0 + l31) * 512 + chunk * 8,
                    (char*)Qs + instr * 1024);
    }
    __syncthreads();

    f32x16 o_acc[4];
    #pragma unroll
    for (int c = 0; c < 4; ++c)
        #pragma unroll
        for (int r = 0; r < 16; ++r) o_acc[c][r] = 0.f;
    float m = -INFINITY, l = 0.f;

    for (int it = 0; it < AITERS; ++it) {
        // ---- QK^T: S^T[32k of wave][32q], 32 MFMAs over d=512
        f32x16 s;
        #pragma unroll
        for (int r = 0; r < 16; ++r) s[r] = 0.f;
        const _Float16* kp = Kp + (((size_t)it * 4 + wave) * 32) * 512;
        #pragma unroll 8
        for (int f = 0; f < 32; ++f) {
            half8 ka = *(const half8*)(kp + f * 512 + lane * 8);
            half8 qb = *(const half8*)(Qs + (2 * f + hi32) * 256 + l31 * 8);
            s = __builtin_amdgcn_mfma_f32_32x32x16_f16(ka, qb, s, 0, 0, 0);
        }

        // ---- tile max for this wave's 32 keys (col = query l31)
        float tmax = s[0];
        #pragma unroll
        for (int r = 1; r < 16; ++r) tmax = fmaxf(tmax, s[r]);
        tmax = fmaxf(tmax, __shfl_xor(tmax, 32));
        if (lane < 32) tm_s[wave][lane] = tmax;
        __syncthreads();   // BAR1: tm_s visible; prev-iter LDS consumers done

        float mn = fmaxf(fmaxf(fmaxf(tm_s[0][l31], tm_s[1][l31]),
                               fmaxf(tm_s[2][l31], tm_s[3][l31])), m);
        float corr = __expf(m - mn);     // exp(-inf)=0 on first tile

        // ---- P = exp(s - mn), write to Pl[it&1] ([kchunk][q][8] layout), psum
        float p[16];
        float psum = 0.f;
        #pragma unroll
        for (int r = 0; r < 16; ++r) { p[r] = __expf(s[r] - mn); psum += p[r]; }
        {
            char* pbuf = (char*)Pl[it & 1];
            #pragma unroll
            for (int g = 0; g < 8; ++g) {
                int r0 = 2 * g;
                int krow = (r0 & 3) + 8 * (r0 >> 2) + 4 * hi32 + 32 * wave;
                *(h2*)(pbuf + ((krow >> 3) * 512 + l31 * 16 + (krow & 7) * 2)) =
                    (h2){(_Float16)p[r0], (_Float16)p[r0 + 1]};
            }
        }
        psum += __shfl_xor(psum, 32);
        if (lane < 32) ls_s[wave][lane] = psum;
        __syncthreads();   // BAR2: P, ls_s visible

        // ---- state update (every wave tracks identical m,l for its q-col l31)
        l = l * corr + (ls_s[0][l31] + ls_s[1][l31]) + (ls_s[2][l31] + ls_s[3][l31]);
        m = mn;

        // ---- rescale O^T, then PV: O^T[128ch slice][32q] += V^T · P^T
        #pragma unroll
        for (int c = 0; c < 4; ++c)
            #pragma unroll
            for (int r = 0; r < 16; ++r) o_acc[c][r] *= corr;

        const _Float16* pbuf = Pl[it & 1];
        #pragma unroll
        for (int kf = 0; kf < 8; ++kf) {
            half8 pfrag = *(const half8*)(pbuf + (2 * kf + hi32) * 256 + l31 * 8);
            #pragma unroll
            for (int cht = 0; cht < 4; ++cht) {
                const _Float16* vp = Vp + ((((size_t)it * 16 + wave * 4 + cht) * 8 + kf)) * 512;
                half8 va = *(const half8*)(vp + lane * 8);
                o_acc[cht] = __builtin_amdgcn_mfma_f32_32x32x16_f16(va, pfrag, o_acc[cht], 0, 0, 0);
            }
        }
        // no BAR3: next iter writes Pl[other buf]; tm_s/ls_s rewrites are
        // separated from this iter's readers by BAR2/BAR1 of the next iter.
    }

    // ---- epilogue: normalized write, ch-major
    float linv = 1.f / l;
    #pragma unroll
    for (int cht = 0; cht < 4; ++cht)
        #pragma unroll
        for (int r = 0; r < 16; ++r) {
            int row = (r & 3) + 8 * (r >> 2) + 4 * hi32;
            enh[(size_t)(wave * 128 + cht * 32 + row) * Nd + q0 + l31] =
                o_acc[cht][r] * linv;
        }
}

// ---------------- BN stats (per channel, double accumulation) ----------------
__global__ __launch_bounds__(256) void bnstats_k(const float* __restrict__ y,
                                                 const float* __restrict__ gamma,
                                                 const float* __restrict__ beta,
                                                 float* __restrict__ stats) {
    const int c = blockIdx.x;
    const int tid = threadIdx.x;
    double s = 0.0, sq = 0.0;
    for (int b = 0; b < Bd; ++b) {
        const float* p = y + (size_t)(b * Cd + c) * HWd;
        for (int i = tid; i < HWd; i += 256) {
            double v = (double)p[i];
            s += v;
            sq += v * v;
        }
    }
    #pragma unroll
    for (int off = 32; off; off >>= 1) {
        s  += __shfl_xor(s, off, 64);
        sq += __shfl_xor(sq, off, 64);
    }
    __shared__ double ss[4], sqs[4];
    int wid = tid >> 6;
    if ((tid & 63) == 0) { ss[wid] = s; sqs[wid] = sq; }
    __syncthreads();
    if (tid == 0) {
        double S = ss[0] + ss[1] + ss[2] + ss[3];
        double Q = sqs[0] + sqs[1] + sqs[2] + sqs[3];
        double mean = S / (double)Nd;
        double var = Q / (double)Nd - mean * mean;
        float inv = (float)(1.0 / sqrt(var + (double)BN_EPS));
        float sc = gamma[c] * inv;
        stats[c] = sc;
        stats[Cd + c] = beta[c] - (float)mean * sc;
    }
}

__global__ __launch_bounds__(256) void bnapply_k(const float* __restrict__ y,
                                                 const float* __restrict__ stats,
                                                 float* __restrict__ out) {
    int idx = blockIdx.x * 256 + threadIdx.x;
    if (idx >= Bd * Cd * HWd) return;
    int c = (idx / HWd) % Cd;
    float v = fmaf(y[idx], stats[c], stats[Cd + c]);
    out[idx] = fmaxf(v, 0.f);
}

extern "C" void kernel_launch(void* const* d_in, const int* in_sizes, int n_in,
                              void* d_out, int out_size, void* d_ws, size_t ws_size,
                              hipStream_t stream) {
    const float* x     = (const float*)d_in[0];
    const float* depth = (const float*)d_in[1];
    const float* w_rgb = (const float*)d_in[2];
    const float* b_rgb = (const float*)d_in[3];
    const float* w_lhs = (const float*)d_in[4];
    const float* b_lhs = (const float*)d_in[5];
    const float* w_rhs = (const float*)d_in[6];
    const float* b_rhs = (const float*)d_in[7];
    const float* w_dec = (const float*)d_in[8];
    const float* b_dec = (const float*)d_in[9];
    const float* gamma = (const float*)d_in[10];
    const float* beta  = (const float*)d_in[11];
    float* out = (float*)d_out;

    char* wsb = (char*)d_ws;
    const size_t NC = (size_t)Nd * Cd;
    _Float16* lhsH = (_Float16*)wsb;                 // 9.44 MB
    _Float16* Kp   = (_Float16*)(wsb + NC * 2);      // 9.44 MB
    _Float16* Vp   = (_Float16*)(wsb + NC * 4);      // 9.44 MB
    float* ybuf    = (float*)(wsb + NC * 6);         // 18.87 MB (BCHW f32)
    float* stats   = (float*)(wsb + NC * 6 + NC * 4);

    dim3 gGemm(Nd / 64, Cd / 64);
    linear_k<0, 0><<<gGemm, 256, 0, stream>>>(depth, w_lhs, b_lhs, lhsH);
    linear_k<0, 3><<<gGemm, 256, 0, stream>>>(depth, w_rhs, b_rhs, Kp);
    linear_k<0, 4><<<gGemm, 256, 0, stream>>>(x, w_rgb, b_rgb, Vp);

    // attention output (ch-major f32, exactly out_size floats) staged in d_out
    attn_v3_k<<<Nd / QBLK, 256, 0, stream>>>(lhsH, Kp, Vp, out);

    // decoder reads ch-major enh (d_out), writes BCHW ybuf
    linear_k<2, 2><<<gGemm, 256, 0, stream>>>(out, w_dec, b_dec, ybuf);

    bnstats_k<<<Cd, 256, 0, stream>>>(ybuf, gamma, beta, stats);
    bnapply_k<<<(Bd * Cd * HWd + 255) / 256, 256, 0, stream>>>(ybuf, stats, out);
}

// Round 7
// 713.453 us; speedup vs baseline: 1.9092x; 1.2954x over previous
//
#include <hip/hip_runtime.h>
#include <math.h>

#define Bd 4
#define Cd 512
#define Hd 48
#define Wd 48
#define HWd (Hd * Wd)          // 2304
#define Nd (Bd * HWd)          // 9216
#define BN_EPS 1e-5f

#define QBLK 32
#define KBLK 128
#define NKS 2
#define KSLEN (Nd / NKS)       // 4608
#define AITERS (KSLEN / KBLK)  // 36

typedef _Float16 half8 __attribute__((ext_vector_type(8)));
typedef _Float16 h4 __attribute__((ext_vector_type(4)));
typedef _Float16 h2 __attribute__((ext_vector_type(2)));
typedef float f32x16 __attribute__((ext_vector_type(16)));

__device__ inline void gload_lds16(const void* g, void* l) {
    __builtin_amdgcn_global_load_lds((const __attribute__((address_space(1))) void*)g,
                                     (__attribute__((address_space(3))) void*)l, 16, 0, 0);
}

// K-packed fragment index: [kbt][kt][f][lane][8]  (key=token n, ch=o)
__device__ __host__ inline size_t kp_idx(int n, int o) {
    return ((((size_t)(n >> 7) * 4 + ((n >> 5) & 3)) * 32 + (o >> 4)) * 64
            + ((n & 31) + 32 * ((o >> 3) & 1))) * 8 + (o & 7);
}
// V-packed fragment index: [kbt][chg][kf][lane][8]  (key=token n, ch=o)
__device__ __host__ inline size_t vp_idx(int n, int o) {
    return ((((size_t)(n >> 7) * 16 + (o >> 5)) * 8 + ((n >> 4) & 7)) * 64
            + ((o & 31) + 32 * ((n >> 3) & 1))) * 8 + (n & 7);
}

// ---------------- tiled fp32 linear (1x1 conv), templated layouts ----------------
// INM: 0 = BCHW f32, 2 = ch-major f32 [Cd][Nd]
// OUTM: 0 = fp16 token-major [Nd][Cd], 2 = f32 BCHW, 3 = fp16 K-packed, 4 = fp16 V-packed
template<int INM, int OUTM>
__global__ __launch_bounds__(256) void linear_k(const float* __restrict__ in,
                                                const float* __restrict__ w,
                                                const float* __restrict__ bias,
                                                void* __restrict__ outp) {
    __shared__ float Asub[16][68];
    __shared__ float Bsub[64][17];

    const int tid = threadIdx.x;
    const int tx = tid & 15;
    const int ty = tid >> 4;
    const int n0 = blockIdx.x * 64;
    const int o0 = blockIdx.y * 64;
    const int b  = n0 / HWd;
    const int hw0 = n0 % HWd;

    float acc[4][4] = {};

    for (int k0 = 0; k0 < Cd; k0 += 16) {
        {
            int r = tid >> 6;
            int col = tid & 63;
            #pragma unroll
            for (int i = 0; i < 4; ++i) {
                int c_l = r * 4 + i;
                if (INM == 0)
                    Asub[c_l][col] = in[(size_t)(b * Cd + k0 + c_l) * HWd + hw0 + col];
                else
                    Asub[c_l][col] = in[(size_t)(k0 + c_l) * Nd + n0 + col];
            }
        }
        {
            int c_l = tid & 15;
            int o_l = tid >> 4;
            #pragma unroll
            for (int i = 0; i < 4; ++i) {
                int o = o_l + 16 * i;
                Bsub[o][c_l] = w[(size_t)(o0 + o) * Cd + k0 + c_l];
            }
        }
        __syncthreads();
        #pragma unroll
        for (int k = 0; k < 16; ++k) {
            float4 av = *(const float4*)&Asub[k][tx * 4];
            float a[4] = {av.x, av.y, av.z, av.w};
            float bb[4];
            #pragma unroll
            for (int j = 0; j < 4; ++j) bb[j] = Bsub[ty * 4 + j][k];
            #pragma unroll
            for (int i = 0; i < 4; ++i)
                #pragma unroll
                for (int j = 0; j < 4; ++j)
                    acc[i][j] = fmaf(a[i], bb[j], acc[i][j]);
        }
        __syncthreads();
    }

    #pragma unroll
    for (int j = 0; j < 4; ++j) {
        float bj = bias[o0 + ty * 4 + j];
        #pragma unroll
        for (int i = 0; i < 4; ++i) acc[i][j] += bj;
    }

    if (OUTM == 0) {
        _Float16* o16 = (_Float16*)outp;
        #pragma unroll
        for (int i = 0; i < 4; ++i)
            #pragma unroll
            for (int j = 0; j < 4; ++j)
                o16[(size_t)(n0 + tx * 4 + i) * Cd + o0 + ty * 4 + j] = (_Float16)acc[i][j];
    } else if (OUTM == 3) {
        _Float16* o16 = (_Float16*)outp;
        #pragma unroll
        for (int i = 0; i < 4; ++i) {
            int n = n0 + tx * 4 + i;
            h4 v = {(_Float16)acc[i][0], (_Float16)acc[i][1],
                    (_Float16)acc[i][2], (_Float16)acc[i][3]};
            *(h4*)(o16 + kp_idx(n, o0 + ty * 4)) = v;
        }
    } else if (OUTM == 4) {
        _Float16* o16 = (_Float16*)outp;
        #pragma unroll
        for (int j = 0; j < 4; ++j) {
            int o = o0 + ty * 4 + j;
            h4 v = {(_Float16)acc[0][j], (_Float16)acc[1][j],
                    (_Float16)acc[2][j], (_Float16)acc[3][j]};
            *(h4*)(o16 + vp_idx(n0 + tx * 4, o)) = v;
        }
    } else {
        float* of = (float*)outp;
        #pragma unroll
        for (int j = 0; j < 4; ++j) {
            int o = o0 + ty * 4 + j;
            size_t base = (size_t)(b * Cd + o) * HWd + hw0 + tx * 4;
            #pragma unroll
            for (int i = 0; i < 4; ++i) of[base + i] = acc[i][j];
        }
    }
}

// ---------------- MFMA flash attention v4: packed streaming + reg-batched loads ----
// 4 waves, QBLK=32 q/block, KBLK=128 keys/iter, NKS=2 key-splits (576 blocks).
// K/V operand batches preloaded into registers (static-indexed arrays) so all
// 32 loads are in flight before the MFMA cluster consumes them.
__global__ __launch_bounds__(256, 2) void attn_v4_k(
    const _Float16* __restrict__ lhsH,   // [Nd][512] token-major
    const _Float16* __restrict__ Kp,     // packed
    const _Float16* __restrict__ Vp,     // packed
    float* __restrict__ part,            // [NKS][Cd][Nd]
    float* __restrict__ marr,            // [NKS][Nd]
    float* __restrict__ larr) {          // [NKS][Nd]
    __shared__ _Float16 Qs[64 * 256];    // [64 chunks][32 q][8] = 32KB
    __shared__ _Float16 Pl[2][16 * 256]; // [16 kchunk][32 q][8] = 8KB each
    __shared__ float tm_s[4][32], ls_s[4][32];

    const int tid = threadIdx.x;
    const int wave = tid >> 6;           // = kt (key sub-tile)
    const int lane = tid & 63;
    const int l31 = lane & 31;
    const int hi32 = lane >> 5;
    const int nqb = Nd / QBLK;           // 288
    const int qb = blockIdx.x % nqb;
    const int ks = blockIdx.x / nqb;
    const int q0 = qb * QBLK;
    const int kbt0 = ks * AITERS;        // base 128-key-tile index

    // ---- stage Q once: operand-major (per-lane global source)
    #pragma unroll
    for (int j = 0; j < 8; ++j) {
        int instr = wave * 8 + j;
        int chunk = 2 * instr + hi32;
        gload_lds16(lhsH + (size_t)(q0 + l31) * 512 + chunk * 8,
                    (char*)Qs + instr * 1024);
    }
    __syncthreads();

    f32x16 o_acc[4];
    #pragma unroll
    for (int c = 0; c < 4; ++c)
        #pragma unroll
        for (int r = 0; r < 16; ++r) o_acc[c][r] = 0.f;
    float m = -INFINITY, l = 0.f;

    for (int it = 0; it < AITERS; ++it) {
        // ---- QK^T: preload K batch into regs, then 32 MFMAs over d=512
        const _Float16* kp = Kp + ((size_t)(kbt0 + it) * 4 + wave) * 32 * 512;
        half8 ka[32];
        #pragma unroll
        for (int f = 0; f < 32; ++f)
            ka[f] = *(const half8*)(kp + (size_t)f * 512 + lane * 8);

        f32x16 s;
        #pragma unroll
        for (int r = 0; r < 16; ++r) s[r] = 0.f;
        __builtin_amdgcn_s_setprio(1);
        #pragma unroll
        for (int f = 0; f < 32; ++f) {
            half8 qb = *(const half8*)(Qs + (2 * f + hi32) * 256 + l31 * 8);
            s = __builtin_amdgcn_mfma_f32_32x32x16_f16(ka[f], qb, s, 0, 0, 0);
        }
        __builtin_amdgcn_s_setprio(0);

        // ---- tile max for this wave's 32 keys (col = query l31)
        float tmax = s[0];
        #pragma unroll
        for (int r = 1; r < 16; ++r) tmax = fmaxf(tmax, s[r]);
        tmax = fmaxf(tmax, __shfl_xor(tmax, 32));
        if (lane < 32) tm_s[wave][lane] = tmax;
        __syncthreads();   // BAR1: tm_s visible; prev-iter LDS consumers done

        float mn = fmaxf(fmaxf(fmaxf(tm_s[0][l31], tm_s[1][l31]),
                               fmaxf(tm_s[2][l31], tm_s[3][l31])), m);
        float corr = __expf(m - mn);     // exp(-inf)=0 on first tile

        // ---- P = exp(s - mn) -> Pl[it&1] ([kchunk][q][8]), psum
        float p[16];
        float psum = 0.f;
        #pragma unroll
        for (int r = 0; r < 16; ++r) { p[r] = __expf(s[r] - mn); psum += p[r]; }
        {
            char* pbuf = (char*)Pl[it & 1];
            #pragma unroll
            for (int g = 0; g < 8; ++g) {
                int r0 = 2 * g;
                int krow = (r0 & 3) + 8 * (r0 >> 2) + 4 * hi32 + 32 * wave;
                *(h2*)(pbuf + ((krow >> 3) * 512 + l31 * 16 + (krow & 7) * 2)) =
                    (h2){(_Float16)p[r0], (_Float16)p[r0 + 1]};
            }
        }
        psum += __shfl_xor(psum, 32);
        if (lane < 32) ls_s[wave][lane] = psum;
        __syncthreads();   // BAR2: P, ls_s visible

        // ---- state update (all waves track identical m,l for q-col l31)
        l = l * corr + (ls_s[0][l31] + ls_s[1][l31]) + (ls_s[2][l31] + ls_s[3][l31]);
        m = mn;

        // ---- PV: preload V batch into regs, rescale O, then 32 MFMAs
        const _Float16* vpb = Vp + (size_t)(kbt0 + it) * 16 * 8 * 512
                            + (size_t)wave * 4 * 8 * 512;
        half8 va[32];
        #pragma unroll
        for (int kf = 0; kf < 8; ++kf)
            #pragma unroll
            for (int cht = 0; cht < 4; ++cht)
                va[kf * 4 + cht] =
                    *(const half8*)(vpb + ((size_t)cht * 8 + kf) * 512 + lane * 8);

        #pragma unroll
        for (int c = 0; c < 4; ++c)
            #pragma unroll
            for (int r = 0; r < 16; ++r) o_acc[c][r] *= corr;

        const _Float16* pbuf = Pl[it & 1];
        __builtin_amdgcn_s_setprio(1);
        #pragma unroll
        for (int kf = 0; kf < 8; ++kf) {
            half8 pfrag = *(const half8*)(pbuf + (2 * kf + hi32) * 256 + l31 * 8);
            #pragma unroll
            for (int cht = 0; cht < 4; ++cht)
                o_acc[cht] = __builtin_amdgcn_mfma_f32_32x32x16_f16(
                    va[kf * 4 + cht], pfrag, o_acc[cht], 0, 0, 0);
        }
        __builtin_amdgcn_s_setprio(0);
        // no BAR3: Pl double-buffered; tm_s/ls_s rewrites fenced by BAR1/BAR2.
    }

    // ---- epilogue: unnormalized partials (ch-major) + (m, l)
    #pragma unroll
    for (int cht = 0; cht < 4; ++cht)
        #pragma unroll
        for (int r = 0; r < 16; ++r) {
            int row = (r & 3) + 8 * (r >> 2) + 4 * hi32;
            part[((size_t)ks * Cd + wave * 128 + cht * 32 + row) * Nd + q0 + l31] =
                o_acc[cht][r];
        }
    if (wave == 0 && lane < 32) {
        marr[(size_t)ks * Nd + q0 + lane] = m;
        larr[(size_t)ks * Nd + q0 + lane] = l;
    }
}

// ---------------- LSE merge of the NKS key-split partials (into part0) ----------
__global__ __launch_bounds__(256) void merge_k(float* __restrict__ part,
                                               const float* __restrict__ marr,
                                               const float* __restrict__ larr) {
    int idx = blockIdx.x * 256 + threadIdx.x;
    if (idx >= Cd * Nd) return;
    int q = idx % Nd;
    float m0 = marr[q], m1 = marr[Nd + q];
    float mm = fmaxf(m0, m1);
    float w0 = __expf(m0 - mm), w1 = __expf(m1 - mm);
    float L = larr[q] * w0 + larr[Nd + q] * w1;
    part[idx] = (part[idx] * w0 + part[(size_t)Cd * Nd + idx] * w1) / L;
}

// ---------------- BN stats (per channel, double accumulation) ----------------
__global__ __launch_bounds__(256) void bnstats_k(const float* __restrict__ y,
                                                 const float* __restrict__ gamma,
                                                 const float* __restrict__ beta,
                                                 float* __restrict__ stats) {
    const int c = blockIdx.x;
    const int tid = threadIdx.x;
    double s = 0.0, sq = 0.0;
    for (int b = 0; b < Bd; ++b) {
        const float* p = y + (size_t)(b * Cd + c) * HWd;
        for (int i = tid; i < HWd; i += 256) {
            double v = (double)p[i];
            s += v;
            sq += v * v;
        }
    }
    #pragma unroll
    for (int off = 32; off; off >>= 1) {
        s  += __shfl_xor(s, off, 64);
        sq += __shfl_xor(sq, off, 64);
    }
    __shared__ double ss[4], sqs[4];
    int wid = tid >> 6;
    if ((tid & 63) == 0) { ss[wid] = s; sqs[wid] = sq; }
    __syncthreads();
    if (tid == 0) {
        double S = ss[0] + ss[1] + ss[2] + ss[3];
        double Q = sqs[0] + sqs[1] + sqs[2] + sqs[3];
        double mean = S / (double)Nd;
        double var = Q / (double)Nd - mean * mean;
        float inv = (float)(1.0 / sqrt(var + (double)BN_EPS));
        float sc = gamma[c] * inv;
        stats[c] = sc;
        stats[Cd + c] = beta[c] - (float)mean * sc;
    }
}

__global__ __launch_bounds__(256) void bnapply_k(const float* __restrict__ y,
                                                 const float* __restrict__ stats,
                                                 float* __restrict__ out) {
    int idx = blockIdx.x * 256 + threadIdx.x;
    if (idx >= Bd * Cd * HWd) return;
    int c = (idx / HWd) % Cd;
    float v = fmaf(y[idx], stats[c], stats[Cd + c]);
    out[idx] = fmaxf(v, 0.f);
}

extern "C" void kernel_launch(void* const* d_in, const int* in_sizes, int n_in,
                              void* d_out, int out_size, void* d_ws, size_t ws_size,
                              hipStream_t stream) {
    const float* x     = (const float*)d_in[0];
    const float* depth = (const float*)d_in[1];
    const float* w_rgb = (const float*)d_in[2];
    const float* b_rgb = (const float*)d_in[3];
    const float* w_lhs = (const float*)d_in[4];
    const float* b_lhs = (const float*)d_in[5];
    const float* w_rhs = (const float*)d_in[6];
    const float* b_rhs = (const float*)d_in[7];
    const float* w_dec = (const float*)d_in[8];
    const float* b_dec = (const float*)d_in[9];
    const float* gamma = (const float*)d_in[10];
    const float* beta  = (const float*)d_in[11];
    float* out = (float*)d_out;

    char* wsb = (char*)d_ws;
    const size_t NC = (size_t)Nd * Cd;
    _Float16* lhsH = (_Float16*)wsb;                 // 9.44 MB
    _Float16* Kp   = (_Float16*)(wsb + NC * 2);      // 9.44 MB
    _Float16* Vp   = (_Float16*)(wsb + NC * 4);      // 9.44 MB
    float* part = (float*)(wsb + NC * 6);            // 2 x Cd x Nd f32 (37.7 MB)
    float* marr = part + (size_t)NKS * NC;
    float* larr = marr + (size_t)NKS * Nd;
    float* stats = larr + (size_t)NKS * Nd;
    float* ybuf = part + NC;                         // reuse part1 after merge

    dim3 gGemm(Nd / 64, Cd / 64);
    linear_k<0, 0><<<gGemm, 256, 0, stream>>>(depth, w_lhs, b_lhs, lhsH);
    linear_k<0, 3><<<gGemm, 256, 0, stream>>>(depth, w_rhs, b_rhs, Kp);
    linear_k<0, 4><<<gGemm, 256, 0, stream>>>(x, w_rgb, b_rgb, Vp);

    attn_v4_k<<<(Nd / QBLK) * NKS, 256, 0, stream>>>(lhsH, Kp, Vp, part, marr, larr);

    merge_k<<<((size_t)Cd * Nd + 255) / 256, 256, 0, stream>>>(part, marr, larr);

    // decoder reads ch-major part0, writes BCHW ybuf (= part1 region, dead)
    linear_k<2, 2><<<gGemm, 256, 0, stream>>>(part, w_dec, b_dec, ybuf);

    bnstats_k<<<Cd, 256, 0, stream>>>(ybuf, gamma, beta, stats);
    bnapply_k<<<(Bd * Cd * HWd + 255) / 256, 256, 0, stream>>>(ybuf, stats, out);
}

// Round 8
// 384.694 us; speedup vs baseline: 3.5408x; 1.8546x over previous
//
#include <hip/hip_runtime.h>
#include <math.h>

#define Bd 4
#define Cd 512
#define Hd 48
#define Wd 48
#define HWd (Hd * Wd)          // 2304
#define Nd (Bd * HWd)          // 9216
#define BN_EPS 1e-5f

#define QBLK 32
#define KBLK 128
#define NKS 4
#define KSLEN (Nd / NKS)       // 2304
#define AITERS (KSLEN / KBLK)  // 18

typedef _Float16 half8 __attribute__((ext_vector_type(8)));
typedef _Float16 h4 __attribute__((ext_vector_type(4)));
typedef float f32x16 __attribute__((ext_vector_type(16)));

__device__ inline void gload_lds16(const void* g, void* l) {
    __builtin_amdgcn_global_load_lds((const __attribute__((address_space(1))) void*)g,
                                     (__attribute__((address_space(3))) void*)l, 16, 0, 0);
}

// ---- shared packed-layout index functions (halves), writer==reader ----
// W operand pack (A-role: row=o,k=c; B-role: col=o,k=c — same register mapping)
__device__ inline size_t wp_idx(int o, int c) {
    return (((size_t)(o >> 5) * 32 + (c >> 4)) * 64 + ((o & 31) + 32 * ((c >> 3) & 1))) * 8 + (c & 7);
}
// Q pack (B-operand of QK: col=q, k=c): [qtile][c>>3][q&31][c&7]
__device__ inline size_t qp_idx(int q, int c) {
    return (((size_t)(q >> 5) * 64 + (c >> 3)) * 32 + (q & 31)) * 8 + (c & 7);
}
// K pack (A-operand of QK: row=key n, k=ch o)
__device__ inline size_t kp_idx(int n, int o) {
    return ((((size_t)(n >> 7) * 4 + ((n >> 5) & 3)) * 32 + (o >> 4)) * 64
            + ((n & 31) + 32 * ((o >> 3) & 1))) * 8 + (o & 7);
}
// V pack (A-operand of PV: row=ch o, k=key n)
__device__ inline size_t vp_idx(int n, int o) {
    return ((((size_t)(n >> 7) * 16 + (o >> 5)) * 8 + ((n >> 4) & 7)) * 64
            + ((o & 31) + 32 * ((n >> 3) & 1))) * 8 + (n & 7);
}

// ---------------- weight pack: f32 [512][512] -> fp16 fragment order ----------------
__global__ __launch_bounds__(256) void wpack_k(const float* __restrict__ w0,
                                               const float* __restrict__ w1,
                                               const float* __restrict__ w2,
                                               const float* __restrict__ w3,
                                               _Float16* __restrict__ p0,
                                               _Float16* __restrict__ p1,
                                               _Float16* __restrict__ p2,
                                               _Float16* __restrict__ p3) {
    const float* w; _Float16* p;
    switch (blockIdx.y) {
        case 0: w = w0; p = p0; break;
        case 1: w = w1; p = p1; break;
        case 2: w = w2; p = p2; break;
        default: w = w3; p = p3; break;
    }
    int idx = blockIdx.x * 256 + threadIdx.x;    // 0..32767
    int o = idx >> 6;
    int cc = (idx & 63) * 8;
    float4 a = *(const float4*)(w + (size_t)o * 512 + cc);
    float4 b = *(const float4*)(w + (size_t)o * 512 + cc + 4);
    half8 v = {(_Float16)a.x, (_Float16)a.y, (_Float16)a.z, (_Float16)a.w,
               (_Float16)b.x, (_Float16)b.y, (_Float16)b.z, (_Float16)b.w};
    *(half8*)(p + wp_idx(o, cc)) = v;            // e=0..7 contiguous, 16B aligned
}

// ---------------- MFMA linear (1x1 conv): 32-token tile, 256-o half ----------------
// INM: 0 = f32 BCHW input, 3 = fp16 ch-major [Cd][Nd] input
// OUTM: 0 = Q-pack, 1 = K-pack, 2 = V-pack (swapped operands), 3 = f32 BCHW out
template<int INM, int OUTM>
__global__ __launch_bounds__(256, 2) void linproj_k(const void* __restrict__ in,
                                                    const _Float16* __restrict__ Wp,
                                                    const float* __restrict__ bias,
                                                    void* __restrict__ outp) {
    constexpr bool SWAP = (OUTM == 2);
    __shared__ _Float16 Xs[16384];               // 32KB operand-major X tile

    const int tid = threadIdx.x;
    const int wave = tid >> 6;
    const int lane = tid & 63;
    const int l31 = lane & 31;
    const int hi32 = lane >> 5;
    const int n0 = blockIdx.x * 32;
    const int by = blockIdx.y;                   // 0..1 (256-o half)
    const int b = n0 / HWd;
    const int hw0 = n0 % HWd;

    // ---- stage X tile (32 tokens x 512 c) into operand-major LDS
    {
        const int t = tid & 31;
        const int c0 = tid >> 5;                 // 0..7
        #pragma unroll 8
        for (int k = 0; k < 64; ++k) {
            int c = c0 + 8 * k;
            float val;
            if (INM == 0)
                val = ((const float*)in)[(size_t)(b * Cd + c) * HWd + hw0 + t];
            else
                val = (float)((const _Float16*)in)[(size_t)c * Nd + n0 + t];
            if (!SWAP)
                Xs[(c >> 3) * 256 + t * 8 + (c & 7)] = (_Float16)val;
            else
                Xs[(c >> 4) * 512 + (t + 32 * ((c >> 3) & 1)) * 8 + (c & 7)] = (_Float16)val;
        }
    }
    __syncthreads();

    #pragma unroll
    for (int ot = 0; ot < 2; ++ot) {
        const int otb = by * 256 + ot * 128 + wave * 32;

        // preload this o-tile's W fragments (32 x half8 = 128 VGPR)
        half8 wa[32];
        const _Float16* wpb = Wp + ((size_t)(otb >> 5) * 32) * 512;
        #pragma unroll
        for (int f = 0; f < 32; ++f)
            wa[f] = *(const half8*)(wpb + (size_t)f * 512 + lane * 8);

        f32x16 acc;
        #pragma unroll
        for (int r = 0; r < 16; ++r) acc[r] = 0.f;

        __builtin_amdgcn_s_setprio(1);
        #pragma unroll
        for (int f = 0; f < 32; ++f) {
            if (!SWAP) {
                half8 xb = *(const half8*)(Xs + (2 * f + hi32) * 256 + l31 * 8);
                acc = __builtin_amdgcn_mfma_f32_32x32x16_f16(wa[f], xb, acc, 0, 0, 0);
            } else {
                half8 xa = *(const half8*)(Xs + f * 512 + lane * 8);
                acc = __builtin_amdgcn_mfma_f32_32x32x16_f16(xa, wa[f], acc, 0, 0, 0);
            }
        }
        __builtin_amdgcn_s_setprio(0);

        // ---- epilogue
        if (OUTM == 0) {                         // Q: (token=col, feat=row)
            _Float16* Qp = (_Float16*)outp;
            #pragma unroll
            for (int q8 = 0; q8 < 4; ++q8) {
                int o = otb + 8 * q8 + 4 * hi32;
                float4 bv = *(const float4*)(bias + o);
                h4 v = {(_Float16)(acc[4 * q8 + 0] + bv.x), (_Float16)(acc[4 * q8 + 1] + bv.y),
                        (_Float16)(acc[4 * q8 + 2] + bv.z), (_Float16)(acc[4 * q8 + 3] + bv.w)};
                *(h4*)(Qp + qp_idx(n0 + l31, o)) = v;
            }
        } else if (OUTM == 1) {                  // K: (key=col, feat=row)
            _Float16* Kp = (_Float16*)outp;
            #pragma unroll
            for (int q8 = 0; q8 < 4; ++q8) {
                int o = otb + 8 * q8 + 4 * hi32;
                float4 bv = *(const float4*)(bias + o);
                h4 v = {(_Float16)(acc[4 * q8 + 0] + bv.x), (_Float16)(acc[4 * q8 + 1] + bv.y),
                        (_Float16)(acc[4 * q8 + 2] + bv.z), (_Float16)(acc[4 * q8 + 3] + bv.w)};
                *(h4*)(Kp + kp_idx(n0 + l31, o)) = v;
            }
        } else if (OUTM == 2) {                  // V (swapped): (ch=col, token=row)
            _Float16* Vp = (_Float16*)outp;
            int o = otb + l31;
            float bc = bias[o];
            #pragma unroll
            for (int q8 = 0; q8 < 4; ++q8) {
                int n = n0 + 8 * q8 + 4 * hi32;
                h4 v = {(_Float16)(acc[4 * q8 + 0] + bc), (_Float16)(acc[4 * q8 + 1] + bc),
                        (_Float16)(acc[4 * q8 + 2] + bc), (_Float16)(acc[4 * q8 + 3] + bc)};
                *(h4*)(Vp + vp_idx(n, o)) = v;
            }
        } else {                                 // decoder: f32 BCHW
            float* of = (float*)outp;
            #pragma unroll
            for (int r = 0; r < 16; ++r) {
                int o = otb + (r & 3) + 8 * (r >> 2) + 4 * hi32;
                of[(size_t)(b * Cd + o) * HWd + hw0 + l31] = acc[r] + bias[o];
            }
        }
    }
}

// ---------------- MFMA flash attention v5: packed streaming, NKS=4 ----------------
__global__ __launch_bounds__(256, 2) void attn_v5_k(
    const _Float16* __restrict__ Qp,     // Q-packed
    const _Float16* __restrict__ Kp,     // K-packed
    const _Float16* __restrict__ Vp,     // V-packed
    _Float16* __restrict__ partH,        // [NKS][Cd][Nd] normalized fp16
    float* __restrict__ marr,            // [NKS][Nd]
    float* __restrict__ larr) {          // [NKS][Nd]
    __shared__ _Float16 Qs[64 * 256];    // [64 chunks][32 q][8] = 32KB
    __shared__ _Float16 Pl[2][16 * 256]; // dbuf, 8KB each
    __shared__ float tm_s[4][32], ls_s[4][32];

    const int tid = threadIdx.x;
    const int wave = tid >> 6;
    const int lane = tid & 63;
    const int l31 = lane & 31;
    const int hi32 = lane >> 5;
    const int nqb = Nd / QBLK;           // 288
    const int qb = blockIdx.x % nqb;
    const int ks = blockIdx.x / nqb;
    const int q0 = qb * QBLK;
    const int kbt0 = ks * AITERS;

    // ---- stage Q tile (contiguous 32KB from Q-pack)
    {
        const _Float16* Qt = Qp + (size_t)(q0 >> 5) * 16384;
        #pragma unroll
        for (int j = 0; j < 8; ++j) {
            int instr = wave * 8 + j;
            gload_lds16(Qt + (size_t)instr * 512 + lane * 8, (char*)Qs + instr * 1024);
        }
    }
    __syncthreads();

    f32x16 o_acc[4];
    #pragma unroll
    for (int c = 0; c < 4; ++c)
        #pragma unroll
        for (int r = 0; r < 16; ++r) o_acc[c][r] = 0.f;
    float m = -INFINITY, l = 0.f;

    for (int it = 0; it < AITERS; ++it) {
        // ---- QK^T: preload K batch, then 32 MFMAs over d=512
        const _Float16* kp = Kp + ((size_t)(kbt0 + it) * 4 + wave) * 32 * 512;
        half8 ka[32];
        #pragma unroll
        for (int f = 0; f < 32; ++f)
            ka[f] = *(const half8*)(kp + (size_t)f * 512 + lane * 8);

        f32x16 s;
        #pragma unroll
        for (int r = 0; r < 16; ++r) s[r] = 0.f;
        __builtin_amdgcn_s_setprio(1);
        #pragma unroll
        for (int f = 0; f < 32; ++f) {
            half8 qb8 = *(const half8*)(Qs + (2 * f + hi32) * 256 + l31 * 8);
            s = __builtin_amdgcn_mfma_f32_32x32x16_f16(ka[f], qb8, s, 0, 0, 0);
        }
        __builtin_amdgcn_s_setprio(0);

        float tmax = s[0];
        #pragma unroll
        for (int r = 1; r < 16; ++r) tmax = fmaxf(tmax, s[r]);
        tmax = fmaxf(tmax, __shfl_xor(tmax, 32));
        if (lane < 32) tm_s[wave][lane] = tmax;
        __syncthreads();   // BAR1

        float mn = fmaxf(fmaxf(fmaxf(tm_s[0][l31], tm_s[1][l31]),
                               fmaxf(tm_s[2][l31], tm_s[3][l31])), m);
        float corr = __expf(m - mn);

        float p[16];
        float psum = 0.f;
        #pragma unroll
        for (int r = 0; r < 16; ++r) { p[r] = __expf(s[r] - mn); psum += p[r]; }
        {
            char* pbuf = (char*)Pl[it & 1];
            #pragma unroll
            for (int g = 0; g < 8; ++g) {
                int r0 = 2 * g;
                int krow = (r0 & 3) + 8 * (r0 >> 2) + 4 * hi32 + 32 * wave;
                _Float16 two[2] = {(_Float16)p[r0], (_Float16)p[r0 + 1]};
                *(unsigned*)(pbuf + ((krow >> 3) * 512 + l31 * 16 + (krow & 7) * 2)) =
                    *(unsigned*)two;
            }
        }
        psum += __shfl_xor(psum, 32);
        if (lane < 32) ls_s[wave][lane] = psum;
        __syncthreads();   // BAR2

        l = l * corr + (ls_s[0][l31] + ls_s[1][l31]) + (ls_s[2][l31] + ls_s[3][l31]);
        m = mn;

        // ---- PV: preload V batch, rescale O, then 32 MFMAs
        const _Float16* vpb = Vp + (size_t)(kbt0 + it) * 16 * 8 * 512
                            + (size_t)wave * 4 * 8 * 512;
        half8 va[32];
        #pragma unroll
        for (int kf = 0; kf < 8; ++kf)
            #pragma unroll
            for (int cht = 0; cht < 4; ++cht)
                va[kf * 4 + cht] =
                    *(const half8*)(vpb + ((size_t)cht * 8 + kf) * 512 + lane * 8);

        #pragma unroll
        for (int c = 0; c < 4; ++c)
            #pragma unroll
            for (int r = 0; r < 16; ++r) o_acc[c][r] *= corr;

        const _Float16* pbuf = Pl[it & 1];
        __builtin_amdgcn_s_setprio(1);
        #pragma unroll
        for (int kf = 0; kf < 8; ++kf) {
            half8 pfrag = *(const half8*)(pbuf + (2 * kf + hi32) * 256 + l31 * 8);
            #pragma unroll
            for (int cht = 0; cht < 4; ++cht)
                o_acc[cht] = __builtin_amdgcn_mfma_f32_32x32x16_f16(
                    va[kf * 4 + cht], pfrag, o_acc[cht], 0, 0, 0);
        }
        __builtin_amdgcn_s_setprio(0);
    }

    // ---- epilogue: NORMALIZED fp16 partials (ch-major) + (m, l)
    float linv = 1.f / l;
    #pragma unroll
    for (int cht = 0; cht < 4; ++cht)
        #pragma unroll
        for (int r = 0; r < 16; ++r) {
            int row = (r & 3) + 8 * (r >> 2) + 4 * hi32;
            partH[((size_t)ks * Cd + wave * 128 + cht * 32 + row) * Nd + q0 + l31] =
                (_Float16)(o_acc[cht][r] * linv);
        }
    if (wave == 0 && lane < 32) {
        marr[(size_t)ks * Nd + q0 + lane] = m;
        larr[(size_t)ks * Nd + q0 + lane] = l;
    }
}

// ---------------- LSE merge of 4 normalized key-split partials (in-place plane 0) --
__global__ __launch_bounds__(256) void merge4_k(_Float16* __restrict__ partH,
                                                const float* __restrict__ marr,
                                                const float* __restrict__ larr) {
    size_t idx = (size_t)blockIdx.x * 256 + threadIdx.x;
    if (idx >= (size_t)Cd * Nd) return;
    int q = (int)(idx % Nd);
    float mv[NKS], wv[NKS];
    float mm = -INFINITY;
    #pragma unroll
    for (int s = 0; s < NKS; ++s) { mv[s] = marr[(size_t)s * Nd + q]; mm = fmaxf(mm, mv[s]); }
    float L = 0.f;
    #pragma unroll
    for (int s = 0; s < NKS; ++s) {
        wv[s] = larr[(size_t)s * Nd + q] * __expf(mv[s] - mm);
        L += wv[s];
    }
    float val = 0.f;
    #pragma unroll
    for (int s = 0; s < NKS; ++s)
        val += wv[s] * (float)partH[(size_t)s * Cd * Nd + idx];
    partH[idx] = (_Float16)(val / L);
}

// ---------------- BN stats (per channel, double accumulation) ----------------
__global__ __launch_bounds__(256) void bnstats_k(const float* __restrict__ y,
                                                 const float* __restrict__ gamma,
                                                 const float* __restrict__ beta,
                                                 float* __restrict__ stats) {
    const int c = blockIdx.x;
    const int tid = threadIdx.x;
    double s = 0.0, sq = 0.0;
    for (int b = 0; b < Bd; ++b) {
        const float* p = y + (size_t)(b * Cd + c) * HWd;
        for (int i = tid; i < HWd; i += 256) {
            double v = (double)p[i];
            s += v;
            sq += v * v;
        }
    }
    #pragma unroll
    for (int off = 32; off; off >>= 1) {
        s  += __shfl_xor(s, off, 64);
        sq += __shfl_xor(sq, off, 64);
    }
    __shared__ double ss[4], sqs[4];
    int wid = tid >> 6;
    if ((tid & 63) == 0) { ss[wid] = s; sqs[wid] = sq; }
    __syncthreads();
    if (tid == 0) {
        double S = ss[0] + ss[1] + ss[2] + ss[3];
        double Q = sqs[0] + sqs[1] + sqs[2] + sqs[3];
        double mean = S / (double)Nd;
        double var = Q / (double)Nd - mean * mean;
        float inv = (float)(1.0 / sqrt(var + (double)BN_EPS));
        float sc = gamma[c] * inv;
        stats[c] = sc;
        stats[Cd + c] = beta[c] - (float)mean * sc;
    }
}

// ---------------- BN apply + ReLU, in-place on d_out ----------------
__global__ __launch_bounds__(256) void bnapply_k(float* __restrict__ y,
                                                 const float* __restrict__ stats) {
    int idx = blockIdx.x * 256 + threadIdx.x;
    if (idx >= Bd * Cd * HWd) return;
    int c = (idx / HWd) % Cd;
    float v = fmaf(y[idx], stats[c], stats[Cd + c]);
    y[idx] = fmaxf(v, 0.f);
}

extern "C" void kernel_launch(void* const* d_in, const int* in_sizes, int n_in,
                              void* d_out, int out_size, void* d_ws, size_t ws_size,
                              hipStream_t stream) {
    const float* x     = (const float*)d_in[0];
    const float* depth = (const float*)d_in[1];
    const float* w_rgb = (const float*)d_in[2];
    const float* b_rgb = (const float*)d_in[3];
    const float* w_lhs = (const float*)d_in[4];
    const float* b_lhs = (const float*)d_in[5];
    const float* w_rhs = (const float*)d_in[6];
    const float* b_rhs = (const float*)d_in[7];
    const float* w_dec = (const float*)d_in[8];
    const float* b_dec = (const float*)d_in[9];
    const float* gamma = (const float*)d_in[10];
    const float* beta  = (const float*)d_in[11];
    float* out = (float*)d_out;

    char* wsb = (char*)d_ws;
    const size_t NC = (size_t)Nd * Cd;               // 4.72M elems
    _Float16* Qp    = (_Float16*)wsb;                // 9.44 MB
    _Float16* Kp    = (_Float16*)(wsb + NC * 2);     // 9.44 MB
    _Float16* Vp    = (_Float16*)(wsb + NC * 4);     // 9.44 MB
    _Float16* partH = (_Float16*)(wsb + NC * 6);     // 4 x 9.44 MB
    float* marr  = (float*)(wsb + NC * 6 + NKS * NC * 2);
    float* larr  = marr + (size_t)NKS * Nd;
    float* stats = larr + (size_t)NKS * Nd;
    _Float16* wpLhs = (_Float16*)(stats + 2 * Cd);   // 4 x 512KB packs
    _Float16* wpRhs = wpLhs + (size_t)Cd * Cd;
    _Float16* wpRgb = wpRhs + (size_t)Cd * Cd;
    _Float16* wpDec = wpRgb + (size_t)Cd * Cd;

    wpack_k<<<dim3(128, 4), 256, 0, stream>>>(w_lhs, w_rhs, w_rgb, w_dec,
                                              wpLhs, wpRhs, wpRgb, wpDec);

    dim3 gLin(Nd / 32, 2);
    linproj_k<0, 0><<<gLin, 256, 0, stream>>>(depth, wpLhs, b_lhs, Qp);
    linproj_k<0, 1><<<gLin, 256, 0, stream>>>(depth, wpRhs, b_rhs, Kp);
    linproj_k<0, 2><<<gLin, 256, 0, stream>>>(x, wpRgb, b_rgb, Vp);

    attn_v5_k<<<(Nd / QBLK) * NKS, 256, 0, stream>>>(Qp, Kp, Vp, partH, marr, larr);

    merge4_k<<<(int)((NC + 255) / 256), 256, 0, stream>>>(partH, marr, larr);

    // decoder reads merged fp16 ch-major (partH plane 0), writes f32 BCHW to d_out
    linproj_k<3, 3><<<gLin, 256, 0, stream>>>(partH, wpDec, b_dec, out);

    bnstats_k<<<Cd, 256, 0, stream>>>(out, gamma, beta, stats);
    bnapply_k<<<(Bd * Cd * HWd + 255) / 256, 256, 0, stream>>>(out, stats);
}

// Round 9
// 371.062 us; speedup vs baseline: 3.6709x; 1.0367x over previous
//
#include <hip/hip_runtime.h>
#include <math.h>

#define Bd 4
#define Cd 512
#define Hd 48
#define Wd 48
#define HWd (Hd * Wd)          // 2304
#define Nd (Bd * HWd)          // 9216
#define BN_EPS 1e-5f

#define QBLK 64
#define KBLK 128
#define NKS 4
#define KSLEN (Nd / NKS)       // 2304
#define AITERS (KSLEN / KBLK)  // 18

typedef _Float16 half8 __attribute__((ext_vector_type(8)));
typedef _Float16 h4 __attribute__((ext_vector_type(4)));
typedef float f32x16 __attribute__((ext_vector_type(16)));

__device__ inline void gload_lds16(const void* g, void* l) {
    __builtin_amdgcn_global_load_lds((const __attribute__((address_space(1))) void*)g,
                                     (__attribute__((address_space(3))) void*)l, 16, 0, 0);
}

// ---- shared packed-layout index functions, writer==reader ----
__device__ inline size_t wp_idx(int o, int c) {
    return (((size_t)(o >> 5) * 32 + (c >> 4)) * 64 + ((o & 31) + 32 * ((c >> 3) & 1))) * 8 + (c & 7);
}
__device__ inline size_t qp_idx(int q, int c) {
    return (((size_t)(q >> 5) * 64 + (c >> 3)) * 32 + (q & 31)) * 8 + (c & 7);
}
__device__ inline size_t kp_idx(int n, int o) {
    return ((((size_t)(n >> 7) * 4 + ((n >> 5) & 3)) * 32 + (o >> 4)) * 64
            + ((n & 31) + 32 * ((o >> 3) & 1))) * 8 + (o & 7);
}
__device__ inline size_t vp_idx(int n, int o) {
    return ((((size_t)(n >> 7) * 16 + (o >> 5)) * 8 + ((n >> 4) & 7)) * 64
            + ((o & 31) + 32 * ((n >> 3) & 1))) * 8 + (n & 7);
}

// ---------------- weight pack: f32 [512][512] -> fp16 fragment order ----------------
__global__ __launch_bounds__(256) void wpack_k(const float* __restrict__ w0,
                                               const float* __restrict__ w1,
                                               const float* __restrict__ w2,
                                               const float* __restrict__ w3,
                                               _Float16* __restrict__ p0,
                                               _Float16* __restrict__ p1,
                                               _Float16* __restrict__ p2,
                                               _Float16* __restrict__ p3) {
    const float* w; _Float16* p;
    switch (blockIdx.y) {
        case 0: w = w0; p = p0; break;
        case 1: w = w1; p = p1; break;
        case 2: w = w2; p = p2; break;
        default: w = w3; p = p3; break;
    }
    int idx = blockIdx.x * 256 + threadIdx.x;
    int o = idx >> 6;
    int cc = (idx & 63) * 8;
    float4 a = *(const float4*)(w + (size_t)o * 512 + cc);
    float4 b = *(const float4*)(w + (size_t)o * 512 + cc + 4);
    half8 v = {(_Float16)a.x, (_Float16)a.y, (_Float16)a.z, (_Float16)a.w,
               (_Float16)b.x, (_Float16)b.y, (_Float16)b.z, (_Float16)b.w};
    *(half8*)(p + wp_idx(o, cc)) = v;
}

// ---------------- MFMA linear (1x1 conv): 32-token tile, 256-o half ----------------
template<int INM, int OUTM>
__global__ __launch_bounds__(256, 2) void linproj_k(const void* __restrict__ in,
                                                    const _Float16* __restrict__ Wp,
                                                    const float* __restrict__ bias,
                                                    void* __restrict__ outp) {
    constexpr bool SWAP = (OUTM == 2);
    __shared__ _Float16 Xs[16384];

    const int tid = threadIdx.x;
    const int wave = tid >> 6;
    const int lane = tid & 63;
    const int l31 = lane & 31;
    const int hi32 = lane >> 5;
    const int n0 = blockIdx.x * 32;
    const int by = blockIdx.y;
    const int b = n0 / HWd;
    const int hw0 = n0 % HWd;

    {
        const int t = tid & 31;
        const int c0 = tid >> 5;
        #pragma unroll 8
        for (int k = 0; k < 64; ++k) {
            int c = c0 + 8 * k;
            float val;
            if (INM == 0)
                val = ((const float*)in)[(size_t)(b * Cd + c) * HWd + hw0 + t];
            else
                val = (float)((const _Float16*)in)[(size_t)c * Nd + n0 + t];
            if (!SWAP)
                Xs[(c >> 3) * 256 + t * 8 + (c & 7)] = (_Float16)val;
            else
                Xs[(c >> 4) * 512 + (t + 32 * ((c >> 3) & 1)) * 8 + (c & 7)] = (_Float16)val;
        }
    }
    __syncthreads();

    #pragma unroll
    for (int ot = 0; ot < 2; ++ot) {
        const int otb = by * 256 + ot * 128 + wave * 32;

        half8 wa[32];
        const _Float16* wpb = Wp + ((size_t)(otb >> 5) * 32) * 512;
        #pragma unroll
        for (int f = 0; f < 32; ++f)
            wa[f] = *(const half8*)(wpb + (size_t)f * 512 + lane * 8);

        f32x16 acc;
        #pragma unroll
        for (int r = 0; r < 16; ++r) acc[r] = 0.f;

        __builtin_amdgcn_s_setprio(1);
        #pragma unroll
        for (int f = 0; f < 32; ++f) {
            if (!SWAP) {
                half8 xb = *(const half8*)(Xs + (2 * f + hi32) * 256 + l31 * 8);
                acc = __builtin_amdgcn_mfma_f32_32x32x16_f16(wa[f], xb, acc, 0, 0, 0);
            } else {
                half8 xa = *(const half8*)(Xs + f * 512 + lane * 8);
                acc = __builtin_amdgcn_mfma_f32_32x32x16_f16(xa, wa[f], acc, 0, 0, 0);
            }
        }
        __builtin_amdgcn_s_setprio(0);

        if (OUTM == 0) {
            _Float16* Qp = (_Float16*)outp;
            #pragma unroll
            for (int q8 = 0; q8 < 4; ++q8) {
                int o = otb + 8 * q8 + 4 * hi32;
                float4 bv = *(const float4*)(bias + o);
                h4 v = {(_Float16)(acc[4 * q8 + 0] + bv.x), (_Float16)(acc[4 * q8 + 1] + bv.y),
                        (_Float16)(acc[4 * q8 + 2] + bv.z), (_Float16)(acc[4 * q8 + 3] + bv.w)};
                *(h4*)(Qp + qp_idx(n0 + l31, o)) = v;
            }
        } else if (OUTM == 1) {
            _Float16* Kp = (_Float16*)outp;
            #pragma unroll
            for (int q8 = 0; q8 < 4; ++q8) {
                int o = otb + 8 * q8 + 4 * hi32;
                float4 bv = *(const float4*)(bias + o);
                h4 v = {(_Float16)(acc[4 * q8 + 0] + bv.x), (_Float16)(acc[4 * q8 + 1] + bv.y),
                        (_Float16)(acc[4 * q8 + 2] + bv.z), (_Float16)(acc[4 * q8 + 3] + bv.w)};
                *(h4*)(Kp + kp_idx(n0 + l31, o)) = v;
            }
        } else if (OUTM == 2) {
            _Float16* Vp = (_Float16*)outp;
            int o = otb + l31;
            float bc = bias[o];
            #pragma unroll
            for (int q8 = 0; q8 < 4; ++q8) {
                int n = n0 + 8 * q8 + 4 * hi32;
                h4 v = {(_Float16)(acc[4 * q8 + 0] + bc), (_Float16)(acc[4 * q8 + 1] + bc),
                        (_Float16)(acc[4 * q8 + 2] + bc), (_Float16)(acc[4 * q8 + 3] + bc)};
                *(h4*)(Vp + vp_idx(n, o)) = v;
            }
        } else {
            float* of = (float*)outp;
            #pragma unroll
            for (int r = 0; r < 16; ++r) {
                int o = otb + (r & 3) + 8 * (r >> 2) + 4 * hi32;
                of[(size_t)(b * Cd + o) * HWd + hw0 + l31] = acc[r] + bias[o];
            }
        }
    }
}

// ---------------- MFMA flash attention v6: QBLK=64, 8 waves, packed streaming ------
// wave = (kt = wave&3 key sub-tile, qg = wave>>2 q sub-tile). Q in LDS (64KB),
// K/V reg-streamed from packed global, P via 16KB LDS (single buffer, 2 barriers).
// Each wave tracks softmax state (m,l) for BOTH q-tiles in scalars.
__global__ __launch_bounds__(512, 2) void attn_v6_k(
    const _Float16* __restrict__ Qp,
    const _Float16* __restrict__ Kp,
    const _Float16* __restrict__ Vp,
    _Float16* __restrict__ partH,        // [NKS][Cd][Nd] normalized fp16
    float* __restrict__ marr,            // [NKS][Nd]
    float* __restrict__ larr) {          // [NKS][Nd]
    __shared__ _Float16 Qs[2 * 16384];   // 64KB: [qt][chunk64][q32][8]
    __shared__ _Float16 Pl[8192];        // 16KB: [qt2][kc8][sub2][q32][e8]
    __shared__ float tm_s[4][64], ls_s[4][64];

    const int tid = threadIdx.x;
    const int wave = tid >> 6;
    const int lane = tid & 63;
    const int l31 = lane & 31;
    const int hi32 = lane >> 5;
    const int kt = wave & 3;
    const int qg = wave >> 2;
    const int nqb = Nd / QBLK;           // 144
    const int qb = blockIdx.x % nqb;
    const int ks = blockIdx.x / nqb;
    const int q0 = qb * QBLK;
    const int kbt0 = ks * AITERS;

    // ---- stage Q (64KB contiguous from Q-pack; two 32-q tiles)
    {
        const _Float16* Qt = Qp + (size_t)(q0 >> 5) * 16384;
        #pragma unroll
        for (int j = 0; j < 8; ++j)
            gload_lds16(Qt + (size_t)j * 4096 + tid * 8,
                        (char*)Qs + j * 8192 + wave * 1024);
    }
    __syncthreads();

    f32x16 o_acc[2][2];                  // [cht][qt]
    #pragma unroll
    for (int c = 0; c < 2; ++c)
        #pragma unroll
        for (int q = 0; q < 2; ++q)
            #pragma unroll
            for (int r = 0; r < 16; ++r) o_acc[c][q][r] = 0.f;
    float m0 = -INFINITY, m1 = -INFINITY, l0 = 0.f, l1 = 0.f;

    for (int it = 0; it < AITERS; ++it) {
        // ---- QK^T: this wave's 32-key tile x its q-tile, 32 MFMAs over d=512
        const _Float16* kp = Kp + ((size_t)(kbt0 + it) * 4 + kt) * 32 * 512;
        half8 ka[32];
        #pragma unroll
        for (int f = 0; f < 32; ++f)
            ka[f] = *(const half8*)(kp + (size_t)f * 512 + lane * 8);

        f32x16 s;
        #pragma unroll
        for (int r = 0; r < 16; ++r) s[r] = 0.f;
        const _Float16* qsb = Qs + qg * 16384;
        __builtin_amdgcn_s_setprio(1);
        #pragma unroll
        for (int f = 0; f < 32; ++f) {
            half8 qb8 = *(const half8*)(qsb + (2 * f + hi32) * 256 + l31 * 8);
            s = __builtin_amdgcn_mfma_f32_32x32x16_f16(ka[f], qb8, s, 0, 0, 0);
        }
        __builtin_amdgcn_s_setprio(0);

        float tmax = s[0];
        #pragma unroll
        for (int r = 1; r < 16; ++r) tmax = fmaxf(tmax, s[r]);
        tmax = fmaxf(tmax, __shfl_xor(tmax, 32));
        if (lane < 32) tm_s[kt][qg * 32 + lane] = tmax;
        __syncthreads();   // BAR1: tm_s visible; prev-iter Pl reads drained

        // new maxes for BOTH q-tiles (per-lane q = l31 within each tile)
        float mn0 = fmaxf(fmaxf(fmaxf(tm_s[0][l31], tm_s[1][l31]),
                                fmaxf(tm_s[2][l31], tm_s[3][l31])), m0);
        float mn1 = fmaxf(fmaxf(fmaxf(tm_s[0][32 + l31], tm_s[1][32 + l31]),
                                fmaxf(tm_s[2][32 + l31], tm_s[3][32 + l31])), m1);
        float corr0 = __expf(m0 - mn0);
        float corr1 = __expf(m1 - mn1);
        float mn_own = qg ? mn1 : mn0;

        // ---- P = exp(s - mn_own) -> Pl (own tile), psum
        float p[16];
        float psum = 0.f;
        #pragma unroll
        for (int r = 0; r < 16; ++r) { p[r] = __expf(s[r] - mn_own); psum += p[r]; }
        #pragma unroll
        for (int g = 0; g < 4; ++g) {
            h4 v = {(_Float16)p[4 * g + 0], (_Float16)p[4 * g + 1],
                    (_Float16)p[4 * g + 2], (_Float16)p[4 * g + 3]};
            *(h4*)(Pl + (qg * 8 + kt * 2 + (g >> 1)) * 512 + (g & 1) * 256
                      + l31 * 8 + 4 * hi32) = v;
        }
        psum += __shfl_xor(psum, 32);
        if (lane < 32) ls_s[kt][qg * 32 + lane] = psum;
        __syncthreads();   // BAR2: Pl, ls_s visible

        l0 = l0 * corr0 + (ls_s[0][l31] + ls_s[1][l31]) + (ls_s[2][l31] + ls_s[3][l31]);
        l1 = l1 * corr1 + (ls_s[0][32 + l31] + ls_s[1][32 + l31])
                        + (ls_s[2][32 + l31] + ls_s[3][32 + l31]);
        m0 = mn0; m1 = mn1;

        // ---- V loads: this wave's 64-ch slice (2 chg groups), all 128 keys
        half8 va[16];                    // [cht*8 + kc]
        #pragma unroll
        for (int cht = 0; cht < 2; ++cht)
            #pragma unroll
            for (int kc = 0; kc < 8; ++kc)
                va[cht * 8 + kc] = *(const half8*)(
                    Vp + (((size_t)(kbt0 + it) * 16 + wave * 2 + cht) * 8 + kc) * 512
                       + lane * 8);

        // ---- rescale O, then PV: 32 MFMAs
        #pragma unroll
        for (int cht = 0; cht < 2; ++cht)
            #pragma unroll
            for (int r = 0; r < 16; ++r) {
                o_acc[cht][0][r] *= corr0;
                o_acc[cht][1][r] *= corr1;
            }

        __builtin_amdgcn_s_setprio(1);
        #pragma unroll
        for (int qt = 0; qt < 2; ++qt)
            #pragma unroll
            for (int kc = 0; kc < 8; ++kc) {
                half8 pfrag = *(const half8*)(Pl + (qt * 8 + kc) * 512
                                                 + hi32 * 256 + l31 * 8);
                #pragma unroll
                for (int cht = 0; cht < 2; ++cht)
                    o_acc[cht][qt] = __builtin_amdgcn_mfma_f32_32x32x16_f16(
                        va[cht * 8 + kc], pfrag, o_acc[cht][qt], 0, 0, 0);
            }
        __builtin_amdgcn_s_setprio(0);
    }

    // ---- epilogue: NORMALIZED fp16 partials (ch-major) + (m, l)
    float li0 = 1.f / l0, li1 = 1.f / l1;
    #pragma unroll
    for (int cht = 0; cht < 2; ++cht)
        #pragma unroll
        for (int qt = 0; qt < 2; ++qt)
            #pragma unroll
            for (int r = 0; r < 16; ++r) {
                int row = (r & 3) + 8 * (r >> 2) + 4 * hi32;
                int ch = wave * 64 + cht * 32 + row;
                int q = q0 + qt * 32 + l31;
                partH[((size_t)ks * Cd + ch) * Nd + q] =
                    (_Float16)(o_acc[cht][qt][r] * (qt ? li1 : li0));
            }
    if (wave == 0 && lane < 32) {
        marr[(size_t)ks * Nd + q0 + lane] = m0;
        larr[(size_t)ks * Nd + q0 + lane] = l0;
        marr[(size_t)ks * Nd + q0 + 32 + lane] = m1;
        larr[(size_t)ks * Nd + q0 + 32 + lane] = l1;
    }
}

// ---------------- LSE merge of 4 normalized key-split partials (plane 0) ----------
__global__ __launch_bounds__(256) void merge4_k(_Float16* __restrict__ partH,
                                                const float* __restrict__ marr,
                                                const float* __restrict__ larr) {
    size_t idx = (size_t)blockIdx.x * 256 + threadIdx.x;
    if (idx >= (size_t)Cd * Nd) return;
    int q = (int)(idx % Nd);
    float mv[NKS], wv[NKS];
    float mm = -INFINITY;
    #pragma unroll
    for (int s = 0; s < NKS; ++s) { mv[s] = marr[(size_t)s * Nd + q]; mm = fmaxf(mm, mv[s]); }
    float L = 0.f;
    #pragma unroll
    for (int s = 0; s < NKS; ++s) {
        wv[s] = larr[(size_t)s * Nd + q] * __expf(mv[s] - mm);
        L += wv[s];
    }
    float val = 0.f;
    #pragma unroll
    for (int s = 0; s < NKS; ++s)
        val += wv[s] * (float)partH[(size_t)s * Cd * Nd + idx];
    partH[idx] = (_Float16)(val / L);
}

// ---------------- BN stats (per channel, double accumulation) ----------------
__global__ __launch_bounds__(256) void bnstats_k(const float* __restrict__ y,
                                                 const float* __restrict__ gamma,
                                                 const float* __restrict__ beta,
                                                 float* __restrict__ stats) {
    const int c = blockIdx.x;
    const int tid = threadIdx.x;
    double s = 0.0, sq = 0.0;
    for (int b = 0; b < Bd; ++b) {
        const float* p = y + (size_t)(b * Cd + c) * HWd;
        for (int i = tid; i < HWd; i += 256) {
            double v = (double)p[i];
            s += v;
            sq += v * v;
        }
    }
    #pragma unroll
    for (int off = 32; off; off >>= 1) {
        s  += __shfl_xor(s, off, 64);
        sq += __shfl_xor(sq, off, 64);
    }
    __shared__ double ss[4], sqs[4];
    int wid = tid >> 6;
    if ((tid & 63) == 0) { ss[wid] = s; sqs[wid] = sq; }
    __syncthreads();
    if (tid == 0) {
        double S = ss[0] + ss[1] + ss[2] + ss[3];
        double Q = sqs[0] + sqs[1] + sqs[2] + sqs[3];
        double mean = S / (double)Nd;
        double var = Q / (double)Nd - mean * mean;
        float inv = (float)(1.0 / sqrt(var + (double)BN_EPS));
        float sc = gamma[c] * inv;
        stats[c] = sc;
        stats[Cd + c] = beta[c] - (float)mean * sc;
    }
}

__global__ __launch_bounds__(256) void bnapply_k(float* __restrict__ y,
                                                 const float* __restrict__ stats) {
    int idx = blockIdx.x * 256 + threadIdx.x;
    if (idx >= Bd * Cd * HWd) return;
    int c = (idx / HWd) % Cd;
    float v = fmaf(y[idx], stats[c], stats[Cd + c]);
    y[idx] = fmaxf(v, 0.f);
}

extern "C" void kernel_launch(void* const* d_in, const int* in_sizes, int n_in,
                              void* d_out, int out_size, void* d_ws, size_t ws_size,
                              hipStream_t stream) {
    const float* x     = (const float*)d_in[0];
    const float* depth = (const float*)d_in[1];
    const float* w_rgb = (const float*)d_in[2];
    const float* b_rgb = (const float*)d_in[3];
    const float* w_lhs = (const float*)d_in[4];
    const float* b_lhs = (const float*)d_in[5];
    const float* w_rhs = (const float*)d_in[6];
    const float* b_rhs = (const float*)d_in[7];
    const float* w_dec = (const float*)d_in[8];
    const float* b_dec = (const float*)d_in[9];
    const float* gamma = (const float*)d_in[10];
    const float* beta  = (const float*)d_in[11];
    float* out = (float*)d_out;

    char* wsb = (char*)d_ws;
    const size_t NC = (size_t)Nd * Cd;
    _Float16* Qp    = (_Float16*)wsb;
    _Float16* Kp    = (_Float16*)(wsb + NC * 2);
    _Float16* Vp    = (_Float16*)(wsb + NC * 4);
    _Float16* partH = (_Float16*)(wsb + NC * 6);
    float* marr  = (float*)(wsb + NC * 6 + NKS * NC * 2);
    float* larr  = marr + (size_t)NKS * Nd;
    float* stats = larr + (size_t)NKS * Nd;
    _Float16* wpLhs = (_Float16*)(stats + 2 * Cd);
    _Float16* wpRhs = wpLhs + (size_t)Cd * Cd;
    _Float16* wpRgb = wpRhs + (size_t)Cd * Cd;
    _Float16* wpDec = wpRgb + (size_t)Cd * Cd;

    wpack_k<<<dim3(128, 4), 256, 0, stream>>>(w_lhs, w_rhs, w_rgb, w_dec,
                                              wpLhs, wpRhs, wpRgb, wpDec);

    dim3 gLin(Nd / 32, 2);
    linproj_k<0, 0><<<gLin, 256, 0, stream>>>(depth, wpLhs, b_lhs, Qp);
    linproj_k<0, 1><<<gLin, 256, 0, stream>>>(depth, wpRhs, b_rhs, Kp);
    linproj_k<0, 2><<<gLin, 256, 0, stream>>>(x, wpRgb, b_rgb, Vp);

    attn_v6_k<<<(Nd / QBLK) * NKS, 512, 0, stream>>>(Qp, Kp, Vp, partH, marr, larr);

    merge4_k<<<(int)((NC + 255) / 256), 256, 0, stream>>>(partH, marr, larr);

    linproj_k<3, 3><<<gLin, 256, 0, stream>>>(partH, wpDec, b_dec, out);

    bnstats_k<<<Cd, 256, 0, stream>>>(out, gamma, beta, stats);
    bnapply_k<<<(Bd * Cd * HWd + 255) / 256, 256, 0, stream>>>(out, stats);
}